// Round 3
// baseline (89.144 us; speedup 1.0000x reference)
//
#include <hip/hip_runtime.h>
#include <math.h>

// (B, N, D) = (32, 128, 128)
#define BATCH 32
#define NN    128
#define BP    136     // bf16 pitch (shorts); rows 272B -> 16B aligned, bank-spread
#define NT    512     // 8 waves
#define EPS   6e-3f   // truncation: all future |prob| <= ||x||_F^2 < EPS once reached
#define SPT   16      // steps i < SPT: sparse wave0 path (block fits one 16x32 MFMA tile)

typedef short frag8 __attribute__((ext_vector_type(8)));   // 8 bf16 = 4 VGPRs
typedef float f32x4 __attribute__((ext_vector_type(4)));   // C/D operand

__device__ __forceinline__ short bf16c(float f) {
    unsigned u = __float_as_uint(f);
    unsigned r = (u + 0x7fffu + ((u >> 16) & 1u)) >> 16;
    return (short)r;
}
__device__ __forceinline__ float bf2f(short s) {
    return __uint_as_float(((unsigned)(unsigned short)s) << 16);
}

// x_new = relu(A @ W): A row-major bf16 [128][BP], W-frags in regs.
// Writes x_new row-major into xrow AND transposed into xT; per-wave partial
// ||x_new||_F^2 into wsp[w] (plain store, no atomic).  NO internal barrier:
// abuf is disjoint from xrow/xT; caller barriers around the phase.
__device__ __forceinline__ void mmw(const short* __restrict__ abuf,
                                    short* __restrict__ xrow,
                                    short* __restrict__ xT,
                                    const frag8 wf[4][2],
                                    int wr, int wc, int l15, int quad,
                                    int lane, int w, float* __restrict__ wsp) {
    const f32x4 z = {0.f, 0.f, 0.f, 0.f};
    f32x4 acc[4][2];
    #pragma unroll
    for (int tr = 0; tr < 4; ++tr) { acc[tr][0] = z; acc[tr][1] = z; }
    #pragma unroll
    for (int ks = 0; ks < 4; ++ks) {
        const int kb = ks * 32 + quad * 8;
        #pragma unroll
        for (int tr = 0; tr < 4; ++tr) {
            frag8 a = *(const frag8*)&abuf[(wr * 64 + tr * 16 + l15) * BP + kb];
            acc[tr][0] = __builtin_amdgcn_mfma_f32_16x16x32_bf16(a, wf[ks][0], acc[tr][0], 0, 0, 0);
            acc[tr][1] = __builtin_amdgcn_mfma_f32_16x16x32_bf16(a, wf[ks][1], acc[tr][1], 0, 0, 0);
        }
    }
    float lss = 0.f;
    #pragma unroll
    for (int tr = 0; tr < 4; ++tr)
        #pragma unroll
        for (int c2 = 0; c2 < 2; ++c2) {
            const int n  = wc * 32 + c2 * 16 + l15;      // out-feature (C col)
            const int m0 = wr * 64 + tr * 16 + quad * 4; // node (C rows, contiguous)
            f32x4 v = acc[tr][c2];
            float r0 = v[0] > 0.f ? v[0] : 0.f;
            float r1 = v[1] > 0.f ? v[1] : 0.f;
            float r2 = v[2] > 0.f ? v[2] : 0.f;
            float r3 = v[3] > 0.f ? v[3] : 0.f;
            lss = fmaf(r0, r0, lss); lss = fmaf(r1, r1, lss);
            lss = fmaf(r2, r2, lss); lss = fmaf(r3, r3, lss);
            short4 p; p.x = bf16c(r0); p.y = bf16c(r1);
            p.z = bf16c(r2); p.w = bf16c(r3);
            *(short4*)&xT[n * BP + m0] = p;              // transposed (feature-major)
            xrow[(m0 + 0) * BP + n] = p.x;               // row-major (node-major)
            xrow[(m0 + 1) * BP + n] = p.y;
            xrow[(m0 + 2) * BP + n] = p.z;
            xrow[(m0 + 3) * BP + n] = p.w;
        }
    #pragma unroll
    for (int off = 32; off >= 1; off >>= 1) lss += __shfl_down(lss, off);
    if (lane == 0) wsp[w] = lss;
}

__global__ __launch_bounds__(NT, 1)
void gcn_kernel(const float* __restrict__ xin,
                const float* __restrict__ W,
                float* __restrict__ out) {
    extern __shared__ char smem_raw[];
    short* adjb  = (short*)smem_raw;              // [128][BP] bf16 carried NORMALIZED matrix
    short* xrow  = adjb + NN * BP;                // [128][BP] bf16 x row-major
    short* xT    = xrow + NN * BP;                // [128][BP] WT stage, then x transposed
    short* ybuf2 = xT + NN * BP;                  // [128][BP] xin stage, then y = adjn@x
    float* prob  = (float*)(ybuf2 + NN * BP);     // [128] masked probs (dense path)
    float* dinv  = prob + NN;                     // [128] (dense path)
    float* rs    = dinv + NN;                     // [128] rowsums of carried normalized matrix
    float* wsum  = rs + NN;                       // [8] per-wave ||x||^2 partials
    __shared__ float wnorm;                       // ||W||_F^2
    __shared__ float sprob;                       // dense path: sum_{j<i} prob[j]
    __shared__ float aii;                         // dense path: adjb[i][i] pre-step

    const int t = threadIdx.x;
    const int b = blockIdx.x;
    const int lane = t & 63, w = t >> 6;          // 8 waves
    const int wr = w >> 2, wc = w & 3;            // F wave tile: rows 64*wr, cols 32*wc
    const int l15 = lane & 15, quad = lane >> 4;

    const float* xin_b = xin + (size_t)b * NN * NN;
    float*       out_b = out + (size_t)b * NN * NN;

    if (t == 0) { wnorm = 0.0f; sprob = 0.0f; }
    __syncthreads();   // order zero-init before atomics below

    // ---- stage: adjb=0, xin->ybuf2 row-major bf16, W->xT transposed bf16 + wnorm
    for (int v = t; v < NN * BP / 2; v += NT) ((int*)adjb)[v] = 0;
    for (int v = t; v < NN * NN / 4; v += NT) {
        float4 f = ((const float4*)xin_b)[v];
        const int node = v >> 5, c = (v & 31) * 4;
        short4 p; p.x = bf16c(f.x); p.y = bf16c(f.y); p.z = bf16c(f.z); p.w = bf16c(f.w);
        *(short4*)&ybuf2[node * BP + c] = p;
    }
    {
        float lw = 0.0f;
        #pragma unroll
        for (int k = 0; k < 8; ++k) {
            const int idx = k * NT + t;           // float4 index into W
            float4 f = ((const float4*)W)[idx];
            lw = fmaf(f.x, f.x, lw); lw = fmaf(f.y, f.y, lw);
            lw = fmaf(f.z, f.z, lw); lw = fmaf(f.w, f.w, lw);
            const int e0 = idx * 4;
            const int d = e0 >> 7, e = e0 & 127;  // W[d][e..e+3]
            xT[(e + 0) * BP + d] = bf16c(f.x);    // WT[e][d]
            xT[(e + 1) * BP + d] = bf16c(f.y);
            xT[(e + 2) * BP + d] = bf16c(f.z);
            xT[(e + 3) * BP + d] = bf16c(f.w);
        }
        #pragma unroll
        for (int off = 32; off >= 1; off >>= 1) lw += __shfl_down(lw, off);
        if (lane == 0) atomicAdd(&wnorm, lw);
    }
    __syncthreads();

    // ---- wfrag: B[k=d][n=e] = W[d][e], read contiguous from staged WT
    frag8 wfrag[4][2];
    #pragma unroll
    for (int ks = 0; ks < 4; ++ks)
        #pragma unroll
        for (int c2 = 0; c2 < 2; ++c2) {
            const int e  = wc * 32 + c2 * 16 + l15;
            const int kb = ks * 32 + quad * 8;
            wfrag[ks][c2] = *(const frag8*)&xT[e * BP + kb];
        }
    if (t < NN) {
        adjb[t * BP + t] = (short)0x3F80;   // bf16 1.0
        out_b[t * NN + t] = 1.0f;
        rs[t] = 1.0f;                       // rowsum of normalized I
    }
    const bool wok = (wnorm <= 1.0f);       // ||W||_2 <= ||W||_F <= 1
    __syncthreads();                        // wfrag reads done before mmw writes xT

    // ---- x0 = relu(xin @ W) -> xrow + xT + wsum
    mmw(ybuf2, xrow, xT, wfrag, wr, wc, l15, quad, lane, w, wsum);
    __syncthreads();
    float ss = 0.f;
    #pragma unroll
    for (int k = 0; k < 8; ++k) ss += wsum[k];
    bool skip = (ss == 0.0f) || (wok && ss < EPS);

    // ---- scan i = 1..127
    for (int i = 1; i < NN; ++i) {
        if (skip) {
            const int i0 = i;
            const int nrow = NN - i0;
            for (int v = t; v < nrow * (NN / 4); v += NT) {
                const int r = i0 + (v >> 5), c = (v & 31) * 4;
                float4 zz = {0.f, 0.f, 0.f, 0.f};
                *(float4*)&out_b[r * NN + c] = zz;
            }
            for (int v = t; v < i0 * nrow; v += NT) {
                const int r = v / nrow, c = i0 + v % nrow;
                out_b[r * NN + c] = 0.f;
            }
            __syncthreads();
            if (t >= i0 && t < NN) out_b[t * NN + t] = 1.0f;
            break;
        }

        if (i < SPT) {
            // ===== SPARSE STEP: carried matrix = I + block[0,i]^2.
            // Wave 0: P,Q,D,E serial (no barriers, shfl-only reductions).
            // Waves 1-7: copy x rows [16,128) -> ybuf2 (y[r>=i] = x[r] exactly).
            if (w == 0) {
                const int ii = i + 1;
                // --- P: prob rows [0,16) via one MFMA row-tile, B = broadcast x_i
                const f32x4 z = {0.f, 0.f, 0.f, 0.f};
                f32x4 pa = z, pb = z;
                #pragma unroll
                for (int ks = 0; ks < 4; ++ks) {
                    const int kb = ks * 32 + quad * 8;
                    frag8 a  = *(const frag8*)&xrow[l15 * BP + kb];
                    frag8 bb = *(const frag8*)&xrow[i * BP + kb];
                    if (ks & 1) pb = __builtin_amdgcn_mfma_f32_16x16x32_bf16(a, bb, pb, 0, 0, 0);
                    else        pa = __builtin_amdgcn_mfma_f32_16x16x32_bf16(a, bb, pa, 0, 0, 0);
                }
                f32x4 pc = pa + pb;      // rows quad*4+r, replicated across l15
                float sp = 0.f;
                if (l15 == 0) {          // lanes 0,16,32,48: 4 rows each
                    #pragma unroll
                    for (int r = 0; r < 4; ++r) {
                        const int j = quad * 4 + r;
                        const float p = pc[r];
                        if (j < i) {
                            const short p16 = bf16c(p);
                            adjb[i * BP + j] = p16;  adjb[j * BP + i] = p16;
                            out_b[i * NN + j] = p;   out_b[j * NN + i] = p;
                            sp += p;
                        }
                    }
                }
                sp += __shfl_down(sp, 32);
                sp += __shfl_down(sp, 16);
                const float sprob_all = __shfl(sp, 0);
                // --- Q: dinv in registers, lane j holds dv for row j (j < ii)
                const int j = lane;
                const int srcl = (j >> 2) << 4;                // quad group owning row j
                const float q0 = __shfl(pc[0], srcl);
                const float q1 = __shfl(pc[1], srcl);
                const float q2 = __shfl(pc[2], srcl);
                const float q3 = __shfl(pc[3], srcl);
                const float t01 = (j & 1) ? q1 : q0;
                const float t23 = (j & 1) ? q3 : q2;
                const float pjrow = (j & 2) ? t23 : t01;       // prob for row j (j<i)
                float dv = 1.0f;
                if (j < ii) {
                    const float deg = (j == i) ? (bf2f(adjb[i * BP + i]) + sprob_all)
                                               : (rs[j] + pjrow);
                    dv = 1.0f / sqrtf(deg);
                }
                // --- D: normalize block [0,ii)^2 in place + rowsums
                for (int r = 0; r <= i; ++r) {
                    const float dr = __shfl(dv, r);
                    float nv = 0.f;
                    if (j < ii) {
                        const float f = bf2f(adjb[r * BP + j]) * dr * dv;
                        adjb[r * BP + j] = bf16c(f);
                        nv = f;
                    }
                    nv += __shfl_down(nv, 8);
                    nv += __shfl_down(nv, 4);
                    nv += __shfl_down(nv, 2);
                    nv += __shfl_down(nv, 1);
                    if (j == 0) rs[r] = nv;
                }
                // --- E: y[0,16) = adjn[0:16,0:32) @ x -> ybuf2 rows [0,16)
                //     (rows [ii,16): adjn row = e_r with diag 1 -> y = x exactly)
                frag8 ae = *(const frag8*)&adjb[l15 * BP + quad * 8];
                #pragma unroll
                for (int f0 = 0; f0 < 8; ++f0) {
                    frag8 bf = *(const frag8*)&xT[(f0 * 16 + l15) * BP + quad * 8];
                    f32x4 yc = {0.f, 0.f, 0.f, 0.f};
                    yc = __builtin_amdgcn_mfma_f32_16x16x32_bf16(ae, bf, yc, 0, 0, 0);
                    const int n  = f0 * 16 + l15;   // feature
                    const int m0 = quad * 4;        // node rows
                    ybuf2[(m0 + 0) * BP + n] = bf16c(yc[0]);
                    ybuf2[(m0 + 1) * BP + n] = bf16c(yc[1]);
                    ybuf2[(m0 + 2) * BP + n] = bf16c(yc[2]);
                    ybuf2[(m0 + 3) * BP + n] = bf16c(yc[3]);
                }
            } else {
                // waves 1-7: y rows [16,128) = x rows (deg=1, dinv=1) -> exact copy
                const int idx = t - 64;              // 0..447
                #pragma unroll
                for (int k = 0; k < 4; ++k) {
                    const int chunk = idx + k * 448; // 0..1791 = 112 rows * 16 frag8
                    const int row = 16 + (chunk >> 4);
                    const int col = (chunk & 15) * 8;
                    *(frag8*)&ybuf2[row * BP + col] = *(const frag8*)&xrow[row * BP + col];
                }
            }
            __syncthreads();
        } else {
            // ===== DENSE STEP (fallback, i >= SPT) =====
            // --- P: prob via MFMA broadcast. Wave w owns rows w*16..w*16+15.
            {
                if (t == 0) aii = bf2f(adjb[i * BP + i]);
                const f32x4 z = {0.f, 0.f, 0.f, 0.f};
                f32x4 pa = z, pb = z;
                #pragma unroll
                for (int ks = 0; ks < 4; ++ks) {
                    const int kb = ks * 32 + quad * 8;
                    frag8 a  = *(const frag8*)&xrow[(w * 16 + l15) * BP + kb];
                    frag8 bb = *(const frag8*)&xrow[i * BP + kb];
                    if (ks & 1) pb = __builtin_amdgcn_mfma_f32_16x16x32_bf16(a, bb, pb, 0, 0, 0);
                    else        pa = __builtin_amdgcn_mfma_f32_16x16x32_bf16(a, bb, pa, 0, 0, 0);
                }
                f32x4 pc = pa + pb;
                float sp = 0.f;
                if (l15 == 0) {
                    #pragma unroll
                    for (int r = 0; r < 4; ++r) {
                        const int j = w * 16 + quad * 4 + r;
                        const float p = pc[r];
                        const bool m = (j < i);
                        prob[j] = m ? p : 0.f;
                        if (m) {
                            const short p16 = bf16c(p);
                            adjb[i * BP + j] = p16;  adjb[j * BP + i] = p16;
                            out_b[i * NN + j] = p;   out_b[j * NN + i] = p;
                            sp += p;
                        }
                    }
                }
                sp += __shfl_down(sp, 32);
                sp += __shfl_down(sp, 16);
                if (lane == 0) atomicAdd(&sprob, sp);
            }
            __syncthreads();

            // --- Q: dinv from incremental degrees
            if (t < NN) {
                const float d = (t == i) ? (aii + sprob) : (rs[t] + prob[t]);
                dinv[t] = 1.0f / sqrtf(d);
            }
            __syncthreads();

            // --- D: normalize carried bf16 matrix in place + new rowsums
            {
                const int r = t >> 2, q = t & 3;
                const float dr = dinv[r];
                float lrs = 0.f;
                #pragma unroll
                for (int g = 0; g < 4; ++g) {
                    const int c = q * 32 + g * 8;
                    frag8 v = *(const frag8*)&adjb[r * BP + c];
                    float dc[8];
                    *(float4*)&dc[0] = *(const float4*)&dinv[c];
                    *(float4*)&dc[4] = *(const float4*)&dinv[c + 4];
                    frag8 o;
                    #pragma unroll
                    for (int k = 0; k < 8; ++k) {
                        const float f = bf2f(v[k]) * dr * dc[k];
                        lrs += f;
                        o[k] = bf16c(f);
                    }
                    *(frag8*)&adjb[r * BP + c] = o;
                }
                lrs += __shfl_down(lrs, 2, 4);
                lrs += __shfl_down(lrs, 1, 4);
                if (q == 0) rs[r] = lrs;
                if (t == NT - 1) sprob = 0.f;      // safe: Q's reads behind barrier
            }
            __syncthreads();

            // --- E: y = adjn @ x -> dead ybuf2
            {
                const f32x4 z = {0.f, 0.f, 0.f, 0.f};
                f32x4 acc[4][2];
                #pragma unroll
                for (int tr = 0; tr < 4; ++tr) { acc[tr][0] = z; acc[tr][1] = z; }
                #pragma unroll
                for (int ks = 0; ks < 4; ++ks) {
                    const int kb = ks * 32 + quad * 8;
                    frag8 b0 = *(const frag8*)&xT[(wc * 32 + l15) * BP + kb];
                    frag8 b1 = *(const frag8*)&xT[(wc * 32 + 16 + l15) * BP + kb];
                    #pragma unroll
                    for (int tr = 0; tr < 4; ++tr) {
                        frag8 a = *(const frag8*)&adjb[(wr * 64 + tr * 16 + l15) * BP + kb];
                        acc[tr][0] = __builtin_amdgcn_mfma_f32_16x16x32_bf16(a, b0, acc[tr][0], 0, 0, 0);
                        acc[tr][1] = __builtin_amdgcn_mfma_f32_16x16x32_bf16(a, b1, acc[tr][1], 0, 0, 0);
                    }
                }
                #pragma unroll
                for (int tr = 0; tr < 4; ++tr)
                    #pragma unroll
                    for (int c2 = 0; c2 < 2; ++c2) {
                        const int n  = wc * 32 + c2 * 16 + l15;
                        const int m0 = wr * 64 + tr * 16 + quad * 4;
                        f32x4 v = acc[tr][c2];
                        ybuf2[(m0 + 0) * BP + n] = bf16c(v[0]);
                        ybuf2[(m0 + 1) * BP + n] = bf16c(v[1]);
                        ybuf2[(m0 + 2) * BP + n] = bf16c(v[2]);
                        ybuf2[(m0 + 3) * BP + n] = bf16c(v[3]);
                    }
            }
            __syncthreads();
        }

        // --- F: x = relu(y @ W) -> xrow + xT + wsum (no inner barrier)
        mmw(ybuf2, xrow, xT, wfrag, wr, wc, l15, quad, lane, w, wsum);
        __syncthreads();
        float ssv = 0.f;
        #pragma unroll
        for (int k = 0; k < 8; ++k) ssv += wsum[k];
        ss = ssv;
        skip = (ss == 0.0f) || (wok && ss < EPS);
    }
}

extern "C" void kernel_launch(void* const* d_in, const int* in_sizes, int n_in,
                              void* d_out, int out_size, void* d_ws, size_t ws_size,
                              hipStream_t stream) {
    const float* x = (const float*)d_in[0];   // (32,128,128) fp32
    const float* W = (const float*)d_in[1];   // (128,128) fp32
    float* out = (float*)d_out;               // (32,128,128) fp32

    const size_t shmem = (size_t)4 * NN * BP * sizeof(short)
                       + (size_t)(3 * NN + 8) * sizeof(float);   // 140,832 B
    hipFuncSetAttribute((const void*)gcn_kernel,
                        hipFuncAttributeMaxDynamicSharedMemorySize, (int)shmem);

    gcn_kernel<<<dim3(BATCH), dim3(NT), shmem, stream>>>(x, W, out);
}

// Round 4
// 74.408 us; speedup vs baseline: 1.1981x; 1.1981x over previous
//
#include <hip/hip_runtime.h>
#include <math.h>

// (B, N, D) = (32, 128, 128)
#define BATCH 32
#define NN    128
#define BP    136     // bf16 pitch (shorts); rows 272B -> 16B aligned, bank-spread
#define NT    512     // 8 waves
#define EPS   6e-3f   // truncation: all future |prob| <= ||x||_F^2 < EPS once reached

typedef short frag8 __attribute__((ext_vector_type(8)));   // 8 bf16 = 4 VGPRs
typedef float f32x4 __attribute__((ext_vector_type(4)));   // C/D operand

__device__ __forceinline__ short bf16c(float f) {
    unsigned u = __float_as_uint(f);
    unsigned r = (u + 0x7fffu + ((u >> 16) & 1u)) >> 16;
    return (short)r;
}
__device__ __forceinline__ float bf2f(short s) {
    return __uint_as_float(((unsigned)(unsigned short)s) << 16);
}

// x_new = relu(A @ W): A row-major bf16 [128][BP], W-frags in regs.
// Writes x_new row-major into xrow AND transposed into xT; accumulates
// ||x_new||_F^2 into *ssp.  NO internal barrier: input and output buffers
// are disjoint (abuf != xrow/xT), caller barriers around the phase.
__device__ __forceinline__ void mmw(const short* __restrict__ abuf,
                                    short* __restrict__ xrow,
                                    short* __restrict__ xT,
                                    const frag8 wf[4][2],
                                    int wr, int wc, int l15, int quad,
                                    int lane, float* ssp) {
    const f32x4 z = {0.f, 0.f, 0.f, 0.f};
    f32x4 acc[4][2];
    #pragma unroll
    for (int tr = 0; tr < 4; ++tr) { acc[tr][0] = z; acc[tr][1] = z; }
    #pragma unroll
    for (int ks = 0; ks < 4; ++ks) {
        const int kb = ks * 32 + quad * 8;
        #pragma unroll
        for (int tr = 0; tr < 4; ++tr) {
            frag8 a = *(const frag8*)&abuf[(wr * 64 + tr * 16 + l15) * BP + kb];
            acc[tr][0] = __builtin_amdgcn_mfma_f32_16x16x32_bf16(a, wf[ks][0], acc[tr][0], 0, 0, 0);
            acc[tr][1] = __builtin_amdgcn_mfma_f32_16x16x32_bf16(a, wf[ks][1], acc[tr][1], 0, 0, 0);
        }
    }
    float lss = 0.f;
    #pragma unroll
    for (int tr = 0; tr < 4; ++tr)
        #pragma unroll
        for (int c2 = 0; c2 < 2; ++c2) {
            const int n  = wc * 32 + c2 * 16 + l15;      // out-feature (C col)
            const int m0 = wr * 64 + tr * 16 + quad * 4; // node (C rows, contiguous)
            f32x4 v = acc[tr][c2];
            float r0 = v[0] > 0.f ? v[0] : 0.f;
            float r1 = v[1] > 0.f ? v[1] : 0.f;
            float r2 = v[2] > 0.f ? v[2] : 0.f;
            float r3 = v[3] > 0.f ? v[3] : 0.f;
            lss = fmaf(r0, r0, lss); lss = fmaf(r1, r1, lss);
            lss = fmaf(r2, r2, lss); lss = fmaf(r3, r3, lss);
            short4 p; p.x = bf16c(r0); p.y = bf16c(r1);
            p.z = bf16c(r2); p.w = bf16c(r3);
            *(short4*)&xT[n * BP + m0] = p;              // transposed (feature-major)
            xrow[(m0 + 0) * BP + n] = p.x;               // row-major (node-major)
            xrow[(m0 + 1) * BP + n] = p.y;
            xrow[(m0 + 2) * BP + n] = p.z;
            xrow[(m0 + 3) * BP + n] = p.w;
        }
    #pragma unroll
    for (int off = 32; off >= 1; off >>= 1) lss += __shfl_down(lss, off);
    if (lane == 0) atomicAdd(ssp, lss);
}

__global__ __launch_bounds__(NT, 1)
void gcn_kernel(const float* __restrict__ xin,
                const float* __restrict__ W,
                float* __restrict__ out) {
    extern __shared__ char smem_raw[];
    short* adjb  = (short*)smem_raw;              // [128][BP] bf16 carried NORMALIZED matrix
    short* xrow  = adjb + NN * BP;                // [128][BP] bf16 x row-major
    short* xT    = xrow + NN * BP;                // [128][BP] WT stage, then x transposed
    short* ybuf2 = xT + NN * BP;                  // [128][BP] xin stage, then y = adjn@x
    float* prob  = (float*)(ybuf2 + NN * BP);     // [128] masked probs (fp32)
    float* dinv  = prob + NN;                     // [128]
    float* rs    = dinv + NN;                     // [128] rowsums of carried normalized matrix
    __shared__ float sumsq;                       // ||x||_F^2
    __shared__ float wnorm;                       // ||W||_F^2
    __shared__ float sprob;                       // sum_{j<i} prob[j]
    __shared__ float aii;                         // adjb[i][i] before step-i writes

    const int t = threadIdx.x;
    const int b = blockIdx.x;
    const int lane = t & 63, w = t >> 6;          // 8 waves
    const int wr = w >> 2, wc = w & 3;            // E/F wave tile: rows 64*wr, cols 32*wc
    const int l15 = lane & 15, quad = lane >> 4;

    const float* xin_b = xin + (size_t)b * NN * NN;
    float*       out_b = out + (size_t)b * NN * NN;

    if (t == 0) { sumsq = 0.0f; wnorm = 0.0f; sprob = 0.0f; }
    __syncthreads();   // order the zero-init before any atomicAdd below

    // ---- stage: adjb=0, xin->ybuf2 row-major bf16, W->xT transposed bf16 + wnorm
    for (int v = t; v < NN * BP / 2; v += NT) ((int*)adjb)[v] = 0;
    for (int v = t; v < NN * NN / 4; v += NT) {
        float4 f = ((const float4*)xin_b)[v];
        const int node = v >> 5, c = (v & 31) * 4;
        short4 p; p.x = bf16c(f.x); p.y = bf16c(f.y); p.z = bf16c(f.z); p.w = bf16c(f.w);
        *(short4*)&ybuf2[node * BP + c] = p;
    }
    {
        float lw = 0.0f;
        #pragma unroll
        for (int k = 0; k < 8; ++k) {
            const int idx = k * NT + t;           // float4 index into W
            float4 f = ((const float4*)W)[idx];
            lw = fmaf(f.x, f.x, lw); lw = fmaf(f.y, f.y, lw);
            lw = fmaf(f.z, f.z, lw); lw = fmaf(f.w, f.w, lw);
            const int e0 = idx * 4;
            const int d = e0 >> 7, e = e0 & 127;  // W[d][e..e+3]
            xT[(e + 0) * BP + d] = bf16c(f.x);    // WT[e][d]
            xT[(e + 1) * BP + d] = bf16c(f.y);
            xT[(e + 2) * BP + d] = bf16c(f.z);
            xT[(e + 3) * BP + d] = bf16c(f.w);
        }
        #pragma unroll
        for (int off = 32; off >= 1; off >>= 1) lw += __shfl_down(lw, off);
        if (lane == 0) atomicAdd(&wnorm, lw);
    }
    __syncthreads();

    // ---- wfrag: B[k=d][n=e] = W[d][e], read contiguous from staged WT
    frag8 wfrag[4][2];
    #pragma unroll
    for (int ks = 0; ks < 4; ++ks)
        #pragma unroll
        for (int c2 = 0; c2 < 2; ++c2) {
            const int e  = wc * 32 + c2 * 16 + l15;
            const int kb = ks * 32 + quad * 8;
            wfrag[ks][c2] = *(const frag8*)&xT[e * BP + kb];
        }
    if (t < NN) {
        adjb[t * BP + t] = (short)0x3F80;   // bf16 1.0
        out_b[t * NN + t] = 1.0f;
        rs[t] = 1.0f;                       // rowsum of normalized I
    }
    const bool wok = (wnorm <= 1.0f);       // ||W||_2 <= ||W||_F <= 1
    __syncthreads();                        // wfrag reads done before mmw writes xT

    // ---- x0 = relu(xin @ W) -> xrow + xT + sumsq   (reads ybuf2: no inner barrier)
    mmw(ybuf2, xrow, xT, wfrag, wr, wc, l15, quad, lane, &sumsq);
    __syncthreads();
    float ss = sumsq;
    bool skip = (ss == 0.0f) || (wok && ss < EPS);

    // ---- scan i = 1..127
    for (int i = 1; i < NN; ++i) {
        if (skip) {
            const int i0 = i;
            const int nrow = NN - i0;
            for (int v = t; v < nrow * (NN / 4); v += NT) {
                const int r = i0 + (v >> 5), c = (v & 31) * 4;
                float4 zz = {0.f, 0.f, 0.f, 0.f};
                *(float4*)&out_b[r * NN + c] = zz;
            }
            for (int v = t; v < i0 * nrow; v += NT) {
                const int r = v / nrow, c = i0 + v % nrow;
                out_b[r * NN + c] = 0.f;
            }
            __syncthreads();
            if (t >= i0 && t < NN) out_b[t * NN + t] = 1.0f;
            break;
        }

        // --- P: prob via MFMA broadcast. Wave w owns rows w*16..w*16+15.
        //     B cols all equal x_i -> every lane holds prob replicated.
        {
            if (t == 0) aii = bf2f(adjb[i * BP + i]);  // [i][i] untouched by this phase
            const f32x4 z = {0.f, 0.f, 0.f, 0.f};
            f32x4 pa = z, pb = z;
            #pragma unroll
            for (int ks = 0; ks < 4; ++ks) {
                const int kb = ks * 32 + quad * 8;
                frag8 a  = *(const frag8*)&xrow[(w * 16 + l15) * BP + kb];
                frag8 bb = *(const frag8*)&xrow[i * BP + kb];   // broadcast read
                if (ks & 1) pb = __builtin_amdgcn_mfma_f32_16x16x32_bf16(a, bb, pb, 0, 0, 0);
                else        pa = __builtin_amdgcn_mfma_f32_16x16x32_bf16(a, bb, pa, 0, 0, 0);
            }
            f32x4 pc = pa + pb;
            float sp = 0.f;
            if (l15 == 0) {                        // lanes 0,16,32,48: 4 probs each
                #pragma unroll
                for (int r = 0; r < 4; ++r) {
                    const int j = w * 16 + quad * 4 + r;
                    const float p = pc[r];
                    const bool m = (j < i);
                    prob[j] = m ? p : 0.f;
                    if (m) {
                        const short pb16 = bf16c(p);
                        adjb[i * BP + j] = pb16;  adjb[j * BP + i] = pb16;
                        out_b[i * NN + j] = p;    out_b[j * NN + i] = p;
                        sp += p;
                    }
                }
            }
            sp += __shfl_down(sp, 32);             // lanes 0+=32, 16+=48
            sp += __shfl_down(sp, 16);             // lane 0 += lane 16
            if (lane == 0) atomicAdd(&sprob, sp);
        }
        __syncthreads();

        // --- Q: dinv from incremental degrees (col/row i were 0 off-diag pre-step)
        if (t < NN) {
            const float d = (t == i) ? (aii + sprob) : (rs[t] + prob[t]);
            dinv[t] = 1.0f / sqrtf(d);
        }
        if (t == NN) sumsq = 0.f;                  // reset for this step's F
        __syncthreads();

        // --- D: normalize carried bf16 matrix in place + new rowsums
        {
            const int r = t >> 2, q = t & 3;
            const float dr = dinv[r];
            float lrs = 0.f;
            #pragma unroll
            for (int g = 0; g < 4; ++g) {
                const int c = q * 32 + g * 8;
                frag8 v = *(const frag8*)&adjb[r * BP + c];
                float dc[8];
                *(float4*)&dc[0] = *(const float4*)&dinv[c];
                *(float4*)&dc[4] = *(const float4*)&dinv[c + 4];
                frag8 o;
                #pragma unroll
                for (int k = 0; k < 8; ++k) {
                    const float f = bf2f(v[k]) * dr * dc[k];
                    lrs += f;
                    o[k] = bf16c(f);
                }
                *(frag8*)&adjb[r * BP + c] = o;
            }
            lrs += __shfl_down(lrs, 2, 4);
            lrs += __shfl_down(lrs, 1, 4);
            if (q == 0) rs[r] = lrs;
            if (t == NT - 1) sprob = 0.f;          // safe: Q's reads are behind a barrier
        }
        __syncthreads();

        // --- E: y = adjn @ x  (A: adjb rows; B: x cols via xT rows; both b128)
        //     writes into dead ybuf2 -> no pre-write drain barrier needed
        {
            const f32x4 z = {0.f, 0.f, 0.f, 0.f};
            f32x4 acc[4][2];
            #pragma unroll
            for (int tr = 0; tr < 4; ++tr) { acc[tr][0] = z; acc[tr][1] = z; }
            #pragma unroll
            for (int ks = 0; ks < 4; ++ks) {
                const int kb = ks * 32 + quad * 8;
                frag8 b0 = *(const frag8*)&xT[(wc * 32 + l15) * BP + kb];
                frag8 b1 = *(const frag8*)&xT[(wc * 32 + 16 + l15) * BP + kb];
                #pragma unroll
                for (int tr = 0; tr < 4; ++tr) {
                    frag8 a = *(const frag8*)&adjb[(wr * 64 + tr * 16 + l15) * BP + kb];
                    acc[tr][0] = __builtin_amdgcn_mfma_f32_16x16x32_bf16(a, b0, acc[tr][0], 0, 0, 0);
                    acc[tr][1] = __builtin_amdgcn_mfma_f32_16x16x32_bf16(a, b1, acc[tr][1], 0, 0, 0);
                }
            }
            #pragma unroll
            for (int tr = 0; tr < 4; ++tr)
                #pragma unroll
                for (int c2 = 0; c2 < 2; ++c2) {
                    const int n  = wc * 32 + c2 * 16 + l15;      // feature (C col)
                    const int m0 = wr * 64 + tr * 16 + quad * 4; // node (C rows)
                    f32x4 v = acc[tr][c2];
                    ybuf2[(m0 + 0) * BP + n] = bf16c(v[0]);      // y row-major [node][d]
                    ybuf2[(m0 + 1) * BP + n] = bf16c(v[1]);
                    ybuf2[(m0 + 2) * BP + n] = bf16c(v[2]);
                    ybuf2[(m0 + 3) * BP + n] = bf16c(v[3]);
                }
        }
        __syncthreads();

        // --- F: x = relu(y @ W) -> xrow + xT + sumsq  (no inner barrier)
        mmw(ybuf2, xrow, xT, wfrag, wr, wc, l15, quad, lane, &sumsq);
        __syncthreads();
        ss = sumsq;
        skip = (ss == 0.0f) || (wok && ss < EPS);
    }
}

extern "C" void kernel_launch(void* const* d_in, const int* in_sizes, int n_in,
                              void* d_out, int out_size, void* d_ws, size_t ws_size,
                              hipStream_t stream) {
    const float* x = (const float*)d_in[0];   // (32,128,128) fp32
    const float* W = (const float*)d_in[1];   // (128,128) fp32
    float* out = (float*)d_out;               // (32,128,128) fp32

    const size_t shmem = (size_t)4 * NN * BP * sizeof(short)
                       + (size_t)3 * NN * sizeof(float);   // 140,800 B
    hipFuncSetAttribute((const void*)gcn_kernel,
                        hipFuncAttributeMaxDynamicSharedMemorySize, (int)shmem);

    gcn_kernel<<<dim3(BATCH), dim3(NT), shmem, stream>>>(x, W, out);
}